// Round 9
// baseline (105.399 us; speedup 1.0000x reference)
//
#include <hip/hip_runtime.h>

// DNA transport NEGF: per (b,e) invert A = (E*I - H) + i*diag(0.5*(gL+gR)),
// DOS = -Im tr(Gr), T = sum_ij gL_i gR_j |Gr_ij|^2, plus H scatter output.
//
// Lane j of a 20-lane subgroup owns column j of A (in-place Gauss-Jordan ->
// same registers end as column j of Gr). 3 subgroups/wave, 4 waves/block.
// Grid = 1024 batches x 9 chunks (12 energies each, flat).
//
// SYMMETRY BROADCAST (R3): no-pivot GJ on complex-symmetric A preserves
// M[i][j] = sigma*M[j][i] (sigma=-1 iff exactly one of i,j processed), so
// the pivot column is readable from each lane's own col[k]: one wave-wide
// ds_write_b64 + 10 broadcast ds_read_b128 per step. Signs fold into FMAs.
//
// MEGA-ASM (R8): R5-R7 proved the register allocator insists on parking
// col[]/quads in AGPRs around C-level asm statements (VGPR_Count 36-52,
// ~95 shuttle movs of ~146 VALU instr/step). Fix: the ENTIRE 20-step loop
// is ONE asm volatile block. Clobbered v0-v49 hold the broadcast column
// (v[2i:2i+1] = element i -> sub-register addressable), pivot math on
// literal regs, col[] pinned via 20 "+v" pair operands. Counted lgkmcnt
// waits; write->read safety via per-wave in-order DS (validated R3-R7).
// Lane-k e_k substitution via mask algebra: tu = t + msk*p (t ~= [1,0] on
// lane k), col[k] = tu - msk*[1,0] -- no per-half cndmask needed.
//
// No pivoting: imag(x^* A x) > 0 for all leading blocks => pivots bounded
// below by min_i 0.5(gL_i+gR_i). Stable in fp32 (R0-R7: absmax <= 3.9e-3).

typedef float f32x2 __attribute__((ext_vector_type(2)));
typedef float f32x4 __attribute__((ext_vector_type(4)));

#define H_N   20
#define NE    100
#define T_OFF 0
#define D_OFF 102400
#define H_OFF 204800

__device__ __forceinline__ int triIdx(int i, int j) {  // i <= j, row-major triu
    return i * H_N - ((i * (i - 1)) >> 1) + (j - i);
}

// --- row updates: col[i] -= (+-s_i)*tu, s_i = broadcast elem i = v[2i:2i+1] ---
// pos (rows i>k):  c.x += s.y*tu.y - s.x*tu.x ; c.y += -s.y*tu.x - s.x*tu.y
#define RP(I, R0, R1) \
  "v_pk_fma_f32 %[c" #I "], v[" #R0 ":" #R1 "], %[tu], %[c" #I "] op_sel:[1,1,0] op_sel_hi:[1,0,1] neg_hi:[1,0,0]\n\t" \
  "v_pk_fma_f32 %[c" #I "], v[" #R0 ":" #R1 "], %[tu], %[c" #I "] op_sel_hi:[0,1,1] neg_lo:[1,0,0] neg_hi:[1,0,0]\n\t"
// neg (rows i<k): mirrored signs
#define RN(I, R0, R1) \
  "v_pk_fma_f32 %[c" #I "], v[" #R0 ":" #R1 "], %[tu], %[c" #I "] op_sel:[1,1,0] op_sel_hi:[1,0,1] neg_lo:[1,0,0]\n\t" \
  "v_pk_fma_f32 %[c" #I "], v[" #R0 ":" #R1 "], %[tu], %[c" #I "] op_sel_hi:[0,1,1]\n\t"

// one quad: counted wait, then its two rows (TA/TB = RN or RP)
#define QD(W, TA, IA, A0, A1, TB, IB, B0, B1) \
  "s_waitcnt lgkmcnt(" #W ")\n\t" TA(IA, A0, A1) TB(IB, B0, B1)

#define QQ0(TA,TB) QD(9, TA,0,0,1,    TB,1,2,3)
#define QQ1(TA,TB) QD(8, TA,2,4,5,    TB,3,6,7)
#define QQ2(TA,TB) QD(7, TA,4,8,9,    TB,5,10,11)
#define QQ3(TA,TB) QD(6, TA,6,12,13,  TB,7,14,15)
#define QQ4(TA,TB) QD(5, TA,8,16,17,  TB,9,18,19)
#define QQ5(TA,TB) QD(4, TA,10,20,21, TB,11,22,23)
#define QQ6(TA,TB) QD(3, TA,12,24,25, TB,13,26,27)
#define QQ7(TA,TB) QD(2, TA,14,28,29, TB,15,30,31)
#define QQ8(TA,TB) QD(1, TA,16,32,33, TB,17,34,35)
#define QQ9(TA,TB) QD(0, TA,18,36,37, TB,19,38,39)

// step prologue: publish col[k], issue 10 broadcast reads, pivot math.
// p=[px,py]=v[40:41]; den=v42; msk=v44 (pair v[44:45], lo used); one=v46;
// [-1,0]=v[48:49]. t = col[k]*p (pk, op_sel); tu = t + msk*p.
#define PRE(K, R0, R1, WK) \
  "ds_write_b64 %[ab2], %[c" #K "]\n\t" \
  "ds_read_b128 v[0:3], %[ab] offset:0\n\t" \
  "ds_read_b128 v[4:7], %[ab] offset:16\n\t" \
  "ds_read_b128 v[8:11], %[ab] offset:32\n\t" \
  "ds_read_b128 v[12:15], %[ab] offset:48\n\t" \
  "ds_read_b128 v[16:19], %[ab] offset:64\n\t" \
  "ds_read_b128 v[20:23], %[ab] offset:80\n\t" \
  "ds_read_b128 v[24:27], %[ab] offset:96\n\t" \
  "ds_read_b128 v[28:31], %[ab] offset:112\n\t" \
  "ds_read_b128 v[32:35], %[ab] offset:128\n\t" \
  "ds_read_b128 v[36:39], %[ab] offset:144\n\t" \
  "s_waitcnt lgkmcnt(" #WK ")\n\t" \
  "v_mul_f32 v42, v" #R0 ", v" #R0 "\n\t" \
  "v_fmac_f32 v42, v" #R1 ", v" #R1 "\n\t" \
  "v_rcp_f32 v42, v42\n\t" \
  "s_nop 1\n\t" \
  "v_mul_f32 v40, v" #R0 ", v42\n\t" \
  "v_mul_f32 v41, -v" #R1 ", v42\n\t" \
  "v_pk_mul_f32 %[t], %[c" #K "], v[40:41] op_sel:[1,1] op_sel_hi:[1,0] neg_lo:[1,0]\n\t" \
  "v_pk_fma_f32 %[t], %[c" #K "], v[40:41], %[t] op_sel_hi:[0,1,1]\n\t" \
  "v_cmp_eq_u32 vcc, " #K ", %[ll]\n\t" \
  "v_cndmask_b32 v44, 0, v46, vcc\n\t" \
  "v_pk_fma_f32 %[tu], v[40:41], v[44:45], %[t] op_sel_hi:[1,0,1]\n\t"

// finalize col[k] = tu - msk*[1,0]  (lane k: ~p ; others: tu = t)
#define POST(K) \
  "v_pk_fma_f32 %[c" #K "], v[44:45], v[48:49], %[tu] op_sel_hi:[0,1,1]\n\t"

__global__ __launch_bounds__(256, 2)
void negf_all(const float* __restrict__ tri,
              const float* __restrict__ GL,
              const float* __restrict__ GR,
              float* __restrict__ out)
{
    __shared__ float Hcm[400];          // column-major: Hcm[c*20 + r] = H[r][c]
    __shared__ float sgL[H_N], sgR[H_N];
    __shared__ f32x4 stage[12][10];     // per-subgroup pivot-column broadcast

    const int blk   = blockIdx.x;
    const int b     = blk / 9;
    const int chunk = blk - b * 9;
    const int tid   = threadIdx.x;

    // ---- stage H (column-major) + gammas into LDS ----
    const float* triB = tri + b * 210;
    #pragma unroll
    for (int u0 = 0; u0 < 2; ++u0) {
        int u = tid + u0 * 256;
        if (u < 400) {
            int c = u / 20, r = u - c * 20;
            int lo = r < c ? r : c;
            int hi = r < c ? c : r;
            Hcm[u] = triB[triIdx(lo, hi)];
        }
    }
    if (tid < H_N) {
        sgL[tid] = GL[b * H_N + tid];
        sgR[tid] = GR[b * H_N + tid];
    }
    __syncthreads();

    // ---- H output (row-major), exact copy of inputs; one block per b ----
    if (chunk == 0) {
        #pragma unroll
        for (int u0 = 0; u0 < 2; ++u0) {
            int u = tid + u0 * 256;
            if (u < 400) {
                int r = u / 20, c = u - r * 20;
                out[H_OFF + b * 400 + u] = Hcm[c * 20 + r];
            }
        }
    }

    const int lane = tid & 63;
    const int wid  = tid >> 6;
    const int sw   = lane / 20;              // 0..2 active, 3 idle
    const int ll   = lane - sw * 20;         // 0..19 row/col id within subgroup
    const int sg   = wid * 3 + (sw < 3 ? sw : 0);
    const int e    = chunk * 12 + sg;
    if (sw == 3 || e >= NE) return;          // no __syncthreads after this point

    const float gj   = sgR[ll];              // gammaR_j for this lane's column
    const float gamj = 0.5f * (sgL[ll] + gj);
    const float E    = fmaf((float)e, 6.0f / 99.0f, -3.0f);

    // build column ll of A
    f32x2 col[H_N];
    #pragma unroll
    for (int i = 0; i < H_N; ++i) {
        float hv = Hcm[ll * 20 + i];
        col[i].x = (i == ll) ? (E - hv) : (-hv);
        col[i].y = (i == ll) ? gamj : 0.0f;
    }

    const unsigned ab  = (unsigned)(size_t)(&stage[sg][0]);  // LDS byte offset
    const unsigned ab2 = ab + (unsigned)ll * 8u;
    const unsigned llu = (unsigned)ll;
    f32x2 t, tu;

    asm volatile(
        "s_waitcnt lgkmcnt(0)\n\t"
        "v_mov_b32 v46, 1.0\n\t"
        "v_mov_b32 v48, -1.0\n\t"
        "v_mov_b32 v49, 0\n\t"
        PRE(0,0,1,9)    QQ0(RP,RP) QQ1(RP,RP) QQ2(RP,RP) QQ3(RP,RP) QQ4(RP,RP) QQ5(RP,RP) QQ6(RP,RP) QQ7(RP,RP) QQ8(RP,RP) QQ9(RP,RP) POST(0)
        PRE(1,2,3,9)    QQ0(RN,RP) QQ1(RP,RP) QQ2(RP,RP) QQ3(RP,RP) QQ4(RP,RP) QQ5(RP,RP) QQ6(RP,RP) QQ7(RP,RP) QQ8(RP,RP) QQ9(RP,RP) POST(1)
        PRE(2,4,5,8)    QQ0(RN,RN) QQ1(RP,RP) QQ2(RP,RP) QQ3(RP,RP) QQ4(RP,RP) QQ5(RP,RP) QQ6(RP,RP) QQ7(RP,RP) QQ8(RP,RP) QQ9(RP,RP) POST(2)
        PRE(3,6,7,8)    QQ0(RN,RN) QQ1(RN,RP) QQ2(RP,RP) QQ3(RP,RP) QQ4(RP,RP) QQ5(RP,RP) QQ6(RP,RP) QQ7(RP,RP) QQ8(RP,RP) QQ9(RP,RP) POST(3)
        PRE(4,8,9,7)    QQ0(RN,RN) QQ1(RN,RN) QQ2(RP,RP) QQ3(RP,RP) QQ4(RP,RP) QQ5(RP,RP) QQ6(RP,RP) QQ7(RP,RP) QQ8(RP,RP) QQ9(RP,RP) POST(4)
        PRE(5,10,11,7)  QQ0(RN,RN) QQ1(RN,RN) QQ2(RN,RP) QQ3(RP,RP) QQ4(RP,RP) QQ5(RP,RP) QQ6(RP,RP) QQ7(RP,RP) QQ8(RP,RP) QQ9(RP,RP) POST(5)
        PRE(6,12,13,6)  QQ0(RN,RN) QQ1(RN,RN) QQ2(RN,RN) QQ3(RP,RP) QQ4(RP,RP) QQ5(RP,RP) QQ6(RP,RP) QQ7(RP,RP) QQ8(RP,RP) QQ9(RP,RP) POST(6)
        PRE(7,14,15,6)  QQ0(RN,RN) QQ1(RN,RN) QQ2(RN,RN) QQ3(RN,RP) QQ4(RP,RP) QQ5(RP,RP) QQ6(RP,RP) QQ7(RP,RP) QQ8(RP,RP) QQ9(RP,RP) POST(7)
        PRE(8,16,17,5)  QQ0(RN,RN) QQ1(RN,RN) QQ2(RN,RN) QQ3(RN,RN) QQ4(RP,RP) QQ5(RP,RP) QQ6(RP,RP) QQ7(RP,RP) QQ8(RP,RP) QQ9(RP,RP) POST(8)
        PRE(9,18,19,5)  QQ0(RN,RN) QQ1(RN,RN) QQ2(RN,RN) QQ3(RN,RN) QQ4(RN,RP) QQ5(RP,RP) QQ6(RP,RP) QQ7(RP,RP) QQ8(RP,RP) QQ9(RP,RP) POST(9)
        PRE(10,20,21,4) QQ0(RN,RN) QQ1(RN,RN) QQ2(RN,RN) QQ3(RN,RN) QQ4(RN,RN) QQ5(RP,RP) QQ6(RP,RP) QQ7(RP,RP) QQ8(RP,RP) QQ9(RP,RP) POST(10)
        PRE(11,22,23,4) QQ0(RN,RN) QQ1(RN,RN) QQ2(RN,RN) QQ3(RN,RN) QQ4(RN,RN) QQ5(RN,RP) QQ6(RP,RP) QQ7(RP,RP) QQ8(RP,RP) QQ9(RP,RP) POST(11)
        PRE(12,24,25,3) QQ0(RN,RN) QQ1(RN,RN) QQ2(RN,RN) QQ3(RN,RN) QQ4(RN,RN) QQ5(RN,RN) QQ6(RP,RP) QQ7(RP,RP) QQ8(RP,RP) QQ9(RP,RP) POST(12)
        PRE(13,26,27,3) QQ0(RN,RN) QQ1(RN,RN) QQ2(RN,RN) QQ3(RN,RN) QQ4(RN,RN) QQ5(RN,RN) QQ6(RN,RP) QQ7(RP,RP) QQ8(RP,RP) QQ9(RP,RP) POST(13)
        PRE(14,28,29,2) QQ0(RN,RN) QQ1(RN,RN) QQ2(RN,RN) QQ3(RN,RN) QQ4(RN,RN) QQ5(RN,RN) QQ6(RN,RN) QQ7(RP,RP) QQ8(RP,RP) QQ9(RP,RP) POST(14)
        PRE(15,30,31,2) QQ0(RN,RN) QQ1(RN,RN) QQ2(RN,RN) QQ3(RN,RN) QQ4(RN,RN) QQ5(RN,RN) QQ6(RN,RN) QQ7(RN,RP) QQ8(RP,RP) QQ9(RP,RP) POST(15)
        PRE(16,32,33,1) QQ0(RN,RN) QQ1(RN,RN) QQ2(RN,RN) QQ3(RN,RN) QQ4(RN,RN) QQ5(RN,RN) QQ6(RN,RN) QQ7(RN,RN) QQ8(RP,RP) QQ9(RP,RP) POST(16)
        PRE(17,34,35,1) QQ0(RN,RN) QQ1(RN,RN) QQ2(RN,RN) QQ3(RN,RN) QQ4(RN,RN) QQ5(RN,RN) QQ6(RN,RN) QQ7(RN,RN) QQ8(RN,RP) QQ9(RP,RP) POST(17)
        PRE(18,36,37,0) QQ0(RN,RN) QQ1(RN,RN) QQ2(RN,RN) QQ3(RN,RN) QQ4(RN,RN) QQ5(RN,RN) QQ6(RN,RN) QQ7(RN,RN) QQ8(RN,RN) QQ9(RP,RP) POST(18)
        PRE(19,38,39,0) QQ0(RN,RN) QQ1(RN,RN) QQ2(RN,RN) QQ3(RN,RN) QQ4(RN,RN) QQ5(RN,RN) QQ6(RN,RN) QQ7(RN,RN) QQ8(RN,RN) QQ9(RN,RP) POST(19)
        : [c0]"+v"(col[0]),  [c1]"+v"(col[1]),  [c2]"+v"(col[2]),  [c3]"+v"(col[3]),
          [c4]"+v"(col[4]),  [c5]"+v"(col[5]),  [c6]"+v"(col[6]),  [c7]"+v"(col[7]),
          [c8]"+v"(col[8]),  [c9]"+v"(col[9]),  [c10]"+v"(col[10]),[c11]"+v"(col[11]),
          [c12]"+v"(col[12]),[c13]"+v"(col[13]),[c14]"+v"(col[14]),[c15]"+v"(col[15]),
          [c16]"+v"(col[16]),[c17]"+v"(col[17]),[c18]"+v"(col[18]),[c19]"+v"(col[19]),
          [t]"=&v"(t), [tu]"=&v"(tu)
        : [ab]"v"(ab), [ab2]"v"(ab2), [ll]"v"(llu)
        : "vcc",
          "v0","v1","v2","v3","v4","v5","v6","v7","v8","v9",
          "v10","v11","v12","v13","v14","v15","v16","v17","v18","v19",
          "v20","v21","v22","v23","v24","v25","v26","v27","v28","v29",
          "v30","v31","v32","v33","v34","v35","v36","v37","v38","v39",
          "v40","v41","v42","v43","v44","v45","v46","v47","v48","v49");

    // ---- epilogue: T partial + diag Im, subgroup reduce, store ----
    float tv = 0.0f, dv = 0.0f;
    #pragma unroll
    for (int i = 0; i < H_N; ++i) {
        float aa = fmaf(col[i].x, col[i].x, col[i].y * col[i].y);
        tv = fmaf(sgL[i], aa, tv);
        dv = (i == ll) ? col[i].y : dv;
    }
    tv *= gj;

    #pragma unroll
    for (int d = 16; d >= 1; d >>= 1) {
        float t2 = __shfl(tv, lane + d, 64);
        float d2 = __shfl(dv, lane + d, 64);
        if (ll + d < 20) { tv += t2; dv += d2; }
    }
    if (ll == 0) {
        out[T_OFF + b * NE + e] = __log10f(fmaxf(tv, 1e-16f));
        out[D_OFF + b * NE + e] = __log10f(fmaxf(-dv, 1e-16f));
    }
}

extern "C" void kernel_launch(void* const* d_in, const int* in_sizes, int n_in,
                              void* d_out, int out_size, void* d_ws, size_t ws_size,
                              hipStream_t stream) {
    const float* tri = (const float*)d_in[0];
    const float* gL  = (const float*)d_in[1];
    const float* gR  = (const float*)d_in[2];
    float* out = (float*)d_out;
    negf_all<<<1024 * 9, 256, 0, stream>>>(tri, gL, gR, out);
}

// Round 10
// 97.973 us; speedup vs baseline: 1.0758x; 1.0758x over previous
//
#include <hip/hip_runtime.h>

// DNA transport NEGF: per (b,e) invert A = (E*I - H) + i*diag(0.5*(gL+gR)),
// DOS = -Im tr(Gr), T = sum_ij gL_i gR_j |Gr_ij|^2, plus H scatter output.
//
// R9 LAYOUT: 10 lanes per matrix, each lane owns TWO interleaved columns
// (ja=2m, jb=2m+1). 6 matrices/wave, 4 waves/block = 24 energies/block,
// grid = 1024 x 5 chunks. DS broadcast instrs are shared per-wave (per-lane
// addressing), so doubling matrices/wave HALVES DS per matrix: R3-R8 were
// DS-pipe-bound (~8.5 cyc/instr x 11 instr/step x 144 passes/CU ~= 105us;
// R5 occ60% == R8 occ36% at same time proved it). 13 DS/step for 6 mats.
//
// SYMMETRY BROADCAST (R3): no-pivot GJ on complex-symmetric A preserves
// M[i][j] = sigma*M[j][i] (sigma=-1 iff exactly one of i,j processed) ->
// pivot row published from each lane's own col[k] (2 ds_write_b64), signs
// folded into pk_fma neg modifiers at consumption.
//
// MEGA-ASM (R8): whole elimination in one asm volatile -> no AGPR shuttles
// (R5-R7: allocator parks arrays in AGPRs around separate asm statements).
// Rotating 4-slot read window (v0-v15), early pivot-quad read (v16-v19),
// counted lgkmcnt; reads issued AFTER the FMAs consuming the slot (WAR-safe,
// DS in-order). Stage stride 176B -> 6 broadcast addrs on disjoint banks.
//
// No pivoting: imag(x^* A x) > 0 for all leading blocks => pivots bounded
// below by min_i 0.5(gL_i+gR_i). Stable in fp32 (R0-R8: absmax <= 3.9e-3).

typedef float f32x2 __attribute__((ext_vector_type(2)));

#define H_N   20
#define NE    100
#define T_OFF 0
#define D_OFF 102400
#define H_OFF 204800
#define NSG   24        // subgroups (matrices) per block
#define SGF   44        // floats per stage region (176 B, bank-disjoint)

__device__ __forceinline__ int triIdx(int i, int j) {  // i <= j, row-major triu
    return i * H_N - ((i * (i - 1)) >> 1) + (j - i);
}

// col OP -= (+s)*tu : lo += s.y*tu.y - s.x*tu.x ; hi += -s.y*tu.x - s.x*tu.y
#define RP(OP, S0, S1, T0, T1) \
  "v_pk_fma_f32 %[" #OP "], v[" #S0 ":" #S1 "], v[" #T0 ":" #T1 "], %[" #OP "] op_sel:[1,1,0] op_sel_hi:[1,0,1] neg_hi:[1,0,0]\n\t" \
  "v_pk_fma_f32 %[" #OP "], v[" #S0 ":" #S1 "], v[" #T0 ":" #T1 "], %[" #OP "] op_sel_hi:[0,1,1] neg_lo:[1,0,0] neg_hi:[1,0,0]\n\t"
// col OP -= (-s)*tu : mirrored signs
#define RN(OP, S0, S1, T0, T1) \
  "v_pk_fma_f32 %[" #OP "], v[" #S0 ":" #S1 "], v[" #T0 ":" #T1 "], %[" #OP "] op_sel:[1,1,0] op_sel_hi:[1,0,1] neg_lo:[1,0,0]\n\t" \
  "v_pk_fma_f32 %[" #OP "], v[" #S0 ":" #S1 "], v[" #T0 ":" #T1 "], %[" #OP "] op_sel_hi:[0,1,1]\n\t"

// one quad: counted wait, 2 rows x 2 cols, then prefetch-read (WAR-safe last)
#define QD(W, SL0,SL1,SH0,SH1, IA, IB, TA, TB, ISS) \
  "s_waitcnt lgkmcnt(" #W ")\n\t" \
  TA(a##IA, SL0, SL1, 24, 25) \
  TA(b##IA, SL0, SL1, 26, 27) \
  TB(a##IB, SH0, SH1, 24, 25) \
  TB(b##IB, SH0, SH1, 26, 27) \
  ISS

#define ISS64  "ds_read_b128 v[0:3], %[ab] offset:64\n\t"
#define ISS80  "ds_read_b128 v[4:7], %[ab] offset:80\n\t"
#define ISS96  "ds_read_b128 v[8:11], %[ab] offset:96\n\t"
#define ISS112 "ds_read_b128 v[12:15], %[ab] offset:112\n\t"
#define ISS128 "ds_read_b128 v[0:3], %[ab] offset:128\n\t"
#define ISS144 "ds_read_b128 v[4:7], %[ab] offset:144\n\t"

#define Q0(TA,TB) QD(3, 0,1,2,3,     0,1,  TA,TB, ISS64)
#define Q1(TA,TB) QD(3, 4,5,6,7,     2,3,  TA,TB, ISS80)
#define Q2(TA,TB) QD(3, 8,9,10,11,   4,5,  TA,TB, ISS96)
#define Q3(TA,TB) QD(3, 12,13,14,15, 6,7,  TA,TB, ISS112)
#define Q4(TA,TB) QD(3, 0,1,2,3,     8,9,  TA,TB, ISS128)
#define Q5(TA,TB) QD(3, 4,5,6,7,     10,11,TA,TB, ISS144)
#define Q6(TA,TB) QD(3, 8,9,10,11,   12,13,TA,TB, )
#define Q7(TA,TB) QD(2, 12,13,14,15, 14,15,TA,TB, )
#define Q8(TA,TB) QD(1, 0,1,2,3,     16,17,TA,TB, )
#define Q9(TA,TB) QD(0, 4,5,6,7,     18,19,TA,TB, )

// step prologue: publish both elems, 1 early pivot read + first 3 quads,
// complex reciprocal p=v[20:21], t/tu for both cols (v[24:25],v[26:27]),
// masks v28/v30 (his zero), then 7th read mid-chain.
#define PRE2(K, P0, P1, KQOFF) \
  "ds_write_b64 %[abw], %[a" #K "]\n\t" \
  "ds_write_b64 %[abw], %[b" #K "] offset:8\n\t" \
  "ds_read_b128 v[16:19], %[ab] offset:" #KQOFF "\n\t" \
  "ds_read_b128 v[0:3], %[ab] offset:0\n\t" \
  "ds_read_b128 v[4:7], %[ab] offset:16\n\t" \
  "ds_read_b128 v[8:11], %[ab] offset:32\n\t" \
  "s_waitcnt lgkmcnt(3)\n\t" \
  "v_mul_f32 v22, v" #P0 ", v" #P0 "\n\t" \
  "v_fmac_f32 v22, v" #P1 ", v" #P1 "\n\t" \
  "v_rcp_f32 v22, v22\n\t" \
  "s_nop 1\n\t" \
  "v_mul_f32 v20, v" #P0 ", v22\n\t" \
  "v_mul_f32 v21, -v" #P1 ", v22\n\t" \
  "ds_read_b128 v[12:15], %[ab] offset:48\n\t" \
  "v_pk_mul_f32 v[24:25], %[a" #K "], v[20:21] op_sel:[1,1] op_sel_hi:[1,0] neg_lo:[1,0]\n\t" \
  "v_pk_fma_f32 v[24:25], %[a" #K "], v[20:21], v[24:25] op_sel_hi:[0,1,1]\n\t" \
  "v_pk_mul_f32 v[26:27], %[b" #K "], v[20:21] op_sel:[1,1] op_sel_hi:[1,0] neg_lo:[1,0]\n\t" \
  "v_pk_fma_f32 v[26:27], %[b" #K "], v[20:21], v[26:27] op_sel_hi:[0,1,1]\n\t" \
  "v_cmp_eq_u32 vcc, " #K ", %[lla]\n\t" \
  "v_cndmask_b32 v28, 0, v23, vcc\n\t" \
  "v_cmp_eq_u32 vcc, " #K ", %[llb]\n\t" \
  "v_cndmask_b32 v30, 0, v23, vcc\n\t" \
  "v_pk_fma_f32 v[24:25], v[20:21], v[28:29], v[24:25] op_sel_hi:[1,0,1]\n\t" \
  "v_pk_fma_f32 v[26:27], v[20:21], v[30:31], v[26:27] op_sel_hi:[1,0,1]\n\t"

// finalize col[k] = tu - msk*[1,0]  (owner lane: p ; others: t)
#define POST2(K) \
  "v_pk_fma_f32 %[a" #K "], v[28:29], v[32:33], v[24:25] op_sel_hi:[0,1,1]\n\t" \
  "v_pk_fma_f32 %[b" #K "], v[30:31], v[32:33], v[26:27] op_sel_hi:[0,1,1]\n\t"

__global__ __launch_bounds__(256, 2)
void negf_all(const float* __restrict__ tri,
              const float* __restrict__ GL,
              const float* __restrict__ GR,
              float* __restrict__ out)
{
    __shared__ float Hcm[400];          // column-major: Hcm[c*20 + r] = H[r][c]
    __shared__ float sgL[H_N], sgR[H_N];
    __shared__ float stage[NSG * SGF];  // 176B-strided broadcast regions

    const int blk   = blockIdx.x;
    const int b     = blk / 5;
    const int chunk = blk - b * 5;
    const int tid   = threadIdx.x;

    // ---- stage H (column-major) + gammas into LDS ----
    const float* triB = tri + b * 210;
    #pragma unroll
    for (int u0 = 0; u0 < 2; ++u0) {
        int u = tid + u0 * 256;
        if (u < 400) {
            int c = u / 20, r = u - c * 20;
            int lo = r < c ? r : c;
            int hi = r < c ? c : r;
            Hcm[u] = triB[triIdx(lo, hi)];
        }
    }
    if (tid < H_N) {
        sgL[tid] = GL[b * H_N + tid];
        sgR[tid] = GR[b * H_N + tid];
    }
    __syncthreads();

    // ---- H output (row-major), exact copy of inputs; one block per b ----
    if (chunk == 0) {
        #pragma unroll
        for (int u0 = 0; u0 < 2; ++u0) {
            int u = tid + u0 * 256;
            if (u < 400) {
                int r = u / 20, c = u - r * 20;
                out[H_OFF + b * 400 + u] = Hcm[c * 20 + r];
            }
        }
    }

    const int lane = tid & 63;
    const int wid  = tid >> 6;
    const int sgw  = lane / 10;              // 0..5 active, 6 idle (lanes 60-63)
    const int m    = lane - sgw * 10;        // 0..9
    const int sgb  = wid * 6 + (sgw < 6 ? sgw : 0);
    const int e    = chunk * 24 + sgb;
    if (sgw == 6 || e >= NE) return;         // no __syncthreads after this

    const int ja = 2 * m, jb = ja + 1;       // this lane's two columns
    const float gja = sgR[ja], gjb = sgR[jb];
    const float gama = 0.5f * (sgL[ja] + gja);
    const float gamb = 0.5f * (sgL[jb] + gjb);
    const float E    = fmaf((float)e, 6.0f / 99.0f, -3.0f);

    // build columns ja, jb of A (vectorized LDS reads: columns contiguous)
    f32x2 ca[H_N], cb[H_N];
    #pragma unroll
    for (int q = 0; q < 5; ++q) {
        float4 ha = *(const float4*)&Hcm[ja * 20 + 4 * q];
        float4 hb = *(const float4*)&Hcm[jb * 20 + 4 * q];
        float va[4] = {ha.x, ha.y, ha.z, ha.w};
        float vb[4] = {hb.x, hb.y, hb.z, hb.w};
        #pragma unroll
        for (int u = 0; u < 4; ++u) {
            int i = 4 * q + u;
            ca[i].x = (i == ja) ? (E - va[u]) : (-va[u]);
            ca[i].y = (i == ja) ? gama : 0.0f;
            cb[i].x = (i == jb) ? (E - vb[u]) : (-vb[u]);
            cb[i].y = (i == jb) ? gamb : 0.0f;
        }
    }

    const unsigned ab  = (unsigned)(size_t)&stage[sgb * SGF];
    const unsigned abw = ab + 16u * (unsigned)m;
    const unsigned jau = (unsigned)ja, jbu = (unsigned)jb;

    asm volatile(
        "s_waitcnt lgkmcnt(0)\n\t"
        "v_mov_b32 v23, 1.0\n\t"
        "v_mov_b32 v29, 0\n\t"
        "v_mov_b32 v31, 0\n\t"
        "v_mov_b32 v32, -1.0\n\t"
        "v_mov_b32 v33, 0\n\t"
        PRE2(0,16,17,0)    Q0(RP,RP) Q1(RP,RP) Q2(RP,RP) Q3(RP,RP) Q4(RP,RP) Q5(RP,RP) Q6(RP,RP) Q7(RP,RP) Q8(RP,RP) Q9(RP,RP) POST2(0)
        PRE2(1,18,19,0)    Q0(RN,RP) Q1(RP,RP) Q2(RP,RP) Q3(RP,RP) Q4(RP,RP) Q5(RP,RP) Q6(RP,RP) Q7(RP,RP) Q8(RP,RP) Q9(RP,RP) POST2(1)
        PRE2(2,16,17,16)   Q0(RN,RN) Q1(RP,RP) Q2(RP,RP) Q3(RP,RP) Q4(RP,RP) Q5(RP,RP) Q6(RP,RP) Q7(RP,RP) Q8(RP,RP) Q9(RP,RP) POST2(2)
        PRE2(3,18,19,16)   Q0(RN,RN) Q1(RN,RP) Q2(RP,RP) Q3(RP,RP) Q4(RP,RP) Q5(RP,RP) Q6(RP,RP) Q7(RP,RP) Q8(RP,RP) Q9(RP,RP) POST2(3)
        PRE2(4,16,17,32)   Q0(RN,RN) Q1(RN,RN) Q2(RP,RP) Q3(RP,RP) Q4(RP,RP) Q5(RP,RP) Q6(RP,RP) Q7(RP,RP) Q8(RP,RP) Q9(RP,RP) POST2(4)
        PRE2(5,18,19,32)   Q0(RN,RN) Q1(RN,RN) Q2(RN,RP) Q3(RP,RP) Q4(RP,RP) Q5(RP,RP) Q6(RP,RP) Q7(RP,RP) Q8(RP,RP) Q9(RP,RP) POST2(5)
        PRE2(6,16,17,48)   Q0(RN,RN) Q1(RN,RN) Q2(RN,RN) Q3(RP,RP) Q4(RP,RP) Q5(RP,RP) Q6(RP,RP) Q7(RP,RP) Q8(RP,RP) Q9(RP,RP) POST2(6)
        PRE2(7,18,19,48)   Q0(RN,RN) Q1(RN,RN) Q2(RN,RN) Q3(RN,RP) Q4(RP,RP) Q5(RP,RP) Q6(RP,RP) Q7(RP,RP) Q8(RP,RP) Q9(RP,RP) POST2(7)
        PRE2(8,16,17,64)   Q0(RN,RN) Q1(RN,RN) Q2(RN,RN) Q3(RN,RN) Q4(RP,RP) Q5(RP,RP) Q6(RP,RP) Q7(RP,RP) Q8(RP,RP) Q9(RP,RP) POST2(8)
        PRE2(9,18,19,64)   Q0(RN,RN) Q1(RN,RN) Q2(RN,RN) Q3(RN,RN) Q4(RN,RP) Q5(RP,RP) Q6(RP,RP) Q7(RP,RP) Q8(RP,RP) Q9(RP,RP) POST2(9)
        PRE2(10,16,17,80)  Q0(RN,RN) Q1(RN,RN) Q2(RN,RN) Q3(RN,RN) Q4(RN,RN) Q5(RP,RP) Q6(RP,RP) Q7(RP,RP) Q8(RP,RP) Q9(RP,RP) POST2(10)
        PRE2(11,18,19,80)  Q0(RN,RN) Q1(RN,RN) Q2(RN,RN) Q3(RN,RN) Q4(RN,RN) Q5(RN,RP) Q6(RP,RP) Q7(RP,RP) Q8(RP,RP) Q9(RP,RP) POST2(11)
        PRE2(12,16,17,96)  Q0(RN,RN) Q1(RN,RN) Q2(RN,RN) Q3(RN,RN) Q4(RN,RN) Q5(RN,RN) Q6(RP,RP) Q7(RP,RP) Q8(RP,RP) Q9(RP,RP) POST2(12)
        PRE2(13,18,19,96)  Q0(RN,RN) Q1(RN,RN) Q2(RN,RN) Q3(RN,RN) Q4(RN,RN) Q5(RN,RN) Q6(RN,RP) Q7(RP,RP) Q8(RP,RP) Q9(RP,RP) POST2(13)
        PRE2(14,16,17,112) Q0(RN,RN) Q1(RN,RN) Q2(RN,RN) Q3(RN,RN) Q4(RN,RN) Q5(RN,RN) Q6(RN,RN) Q7(RP,RP) Q8(RP,RP) Q9(RP,RP) POST2(14)
        PRE2(15,18,19,112) Q0(RN,RN) Q1(RN,RN) Q2(RN,RN) Q3(RN,RN) Q4(RN,RN) Q5(RN,RN) Q6(RN,RN) Q7(RN,RP) Q8(RP,RP) Q9(RP,RP) POST2(15)
        PRE2(16,16,17,128) Q0(RN,RN) Q1(RN,RN) Q2(RN,RN) Q3(RN,RN) Q4(RN,RN) Q5(RN,RN) Q6(RN,RN) Q7(RN,RN) Q8(RP,RP) Q9(RP,RP) POST2(16)
        PRE2(17,18,19,128) Q0(RN,RN) Q1(RN,RN) Q2(RN,RN) Q3(RN,RN) Q4(RN,RN) Q5(RN,RN) Q6(RN,RN) Q7(RN,RN) Q8(RN,RP) Q9(RP,RP) POST2(17)
        PRE2(18,16,17,144) Q0(RN,RN) Q1(RN,RN) Q2(RN,RN) Q3(RN,RN) Q4(RN,RN) Q5(RN,RN) Q6(RN,RN) Q7(RN,RN) Q8(RN,RN) Q9(RP,RP) POST2(18)
        PRE2(19,18,19,144) Q0(RN,RN) Q1(RN,RN) Q2(RN,RN) Q3(RN,RN) Q4(RN,RN) Q5(RN,RN) Q6(RN,RN) Q7(RN,RN) Q8(RN,RN) Q9(RN,RP) POST2(19)
        : [a0]"+v"(ca[0]),  [a1]"+v"(ca[1]),  [a2]"+v"(ca[2]),  [a3]"+v"(ca[3]),
          [a4]"+v"(ca[4]),  [a5]"+v"(ca[5]),  [a6]"+v"(ca[6]),  [a7]"+v"(ca[7]),
          [a8]"+v"(ca[8]),  [a9]"+v"(ca[9]),  [a10]"+v"(ca[10]),[a11]"+v"(ca[11]),
          [a12]"+v"(ca[12]),[a13]"+v"(ca[13]),[a14]"+v"(ca[14]),[a15]"+v"(ca[15]),
          [a16]"+v"(ca[16]),[a17]"+v"(ca[17]),[a18]"+v"(ca[18]),[a19]"+v"(ca[19]),
          [b0]"+v"(cb[0]),  [b1]"+v"(cb[1]),  [b2]"+v"(cb[2]),  [b3]"+v"(cb[3]),
          [b4]"+v"(cb[4]),  [b5]"+v"(cb[5]),  [b6]"+v"(cb[6]),  [b7]"+v"(cb[7]),
          [b8]"+v"(cb[8]),  [b9]"+v"(cb[9]),  [b10]"+v"(cb[10]),[b11]"+v"(cb[11]),
          [b12]"+v"(cb[12]),[b13]"+v"(cb[13]),[b14]"+v"(cb[14]),[b15]"+v"(cb[15]),
          [b16]"+v"(cb[16]),[b17]"+v"(cb[17]),[b18]"+v"(cb[18]),[b19]"+v"(cb[19])
        : [ab]"v"(ab), [abw]"v"(abw), [lla]"v"(jau), [llb]"v"(jbu)
        : "vcc",
          "v0","v1","v2","v3","v4","v5","v6","v7","v8","v9",
          "v10","v11","v12","v13","v14","v15","v16","v17","v18","v19",
          "v20","v21","v22","v23","v24","v25","v26","v27","v28","v29",
          "v30","v31","v32","v33");

    // ---- epilogue: T partials for both columns + diag Im, 10-lane reduce ----
    float tva = 0.0f, tvb = 0.0f;
    #pragma unroll
    for (int q = 0; q < 5; ++q) {
        float4 g = *(const float4*)&sgL[4 * q];
        float gg[4] = {g.x, g.y, g.z, g.w};
        #pragma unroll
        for (int u = 0; u < 4; ++u) {
            int i = 4 * q + u;
            tva = fmaf(gg[u], fmaf(ca[i].x, ca[i].x, ca[i].y * ca[i].y), tva);
            tvb = fmaf(gg[u], fmaf(cb[i].x, cb[i].x, cb[i].y * cb[i].y), tvb);
        }
    }
    float tv = gja * tva + gjb * tvb;
    float dv = 0.0f;
    #pragma unroll
    for (int i = 0; i < H_N; ++i) {
        dv += ((i == ja) ? ca[i].y : 0.0f) + ((i == jb) ? cb[i].y : 0.0f);
    }

    #pragma unroll
    for (int d = 8; d >= 1; d >>= 1) {
        float t2 = __shfl(tv, lane + d, 64);
        float d2 = __shfl(dv, lane + d, 64);
        if (m + d < 10) { tv += t2; dv += d2; }
    }
    if (m == 0) {
        out[T_OFF + b * NE + e] = __log10f(fmaxf(tv, 1e-16f));
        out[D_OFF + b * NE + e] = __log10f(fmaxf(-dv, 1e-16f));
    }
}

extern "C" void kernel_launch(void* const* d_in, const int* in_sizes, int n_in,
                              void* d_out, int out_size, void* d_ws, size_t ws_size,
                              hipStream_t stream) {
    const float* tri = (const float*)d_in[0];
    const float* gL  = (const float*)d_in[1];
    const float* gR  = (const float*)d_in[2];
    float* out = (float*)d_out;
    negf_all<<<1024 * 5, 256, 0, stream>>>(tri, gL, gR, out);
}

// Round 11
// 88.341 us; speedup vs baseline: 1.1931x; 1.1090x over previous
//
#include <hip/hip_runtime.h>

// DNA transport NEGF: per (b,e) invert A = (E*I - H) + i*diag(0.5*(gL+gR)),
// DOS = -Im tr(Gr), T = sum_ij gL_i gR_j |Gr_ij|^2, plus H scatter output.
//
// R10 TRIANGULAR GJ: R5-R9 counters showed VALUBusy*dur ~= const -> FP32
// pipe-bound (pk_fma = 4 cyc on SIMD-32; packing cuts instrs, not FLOPs).
// Cut the FLOPs: store only rows 0..j of each column (complex-symmetric
// matrix => in-place no-pivot GJ keeps M[i][j] = +-M[j][i]). 5 lanes per
// matrix, lane m owns cols j = 5c+m (slots c=0..3, rows 0..5c+4 issued ->
// 50 row-updates/step serving 12 matrices/wave vs R9's 80 serving 6).
//
// PIVOT-COLUMN broadcast (not row): y_i = M[i][k]. For i<=k these are the
// col-k owner's rows 0..k (burst, exec-masked to 12 owner lanes, one per
// matrix). For i>k: y_i = M[i][k] = M[k][i] (both unprocessed) = col-i
// owner's row k (one masked ds_write_b64 per slot). Updates are then
// SIGN-FREE: col_j[i] -= y_i * t_j; t_j = col_j[k]*p (j>=k, own register)
// or t_j = -y_j*p (j<k, from broadcast). Row k is updated uniformly (keeps
// the quad stream k-independent -> one ALLQ macro) and overwritten after.
// Out-of-triangle registers: zero-init, stay finite, masked in epilogue.
//
// 64-thread blocks (1 wave, no __syncthreads, per-wave H staging), grid =
// 1024 b x 9 chunks x 12 energies. Mega-asm (R8 lesson: only way to stop
// the allocator's AGPR shuttling) with counted lgkmcnt (R9-validated).
//
// No pivoting: imag(x^* A x) > 0 for all leading blocks => pivots bounded
// below by min_i 0.5(gL_i+gR_i). Stable in fp32 (R0-R9: absmax <= 3.9e-3).

typedef float f32x2 __attribute__((ext_vector_type(2)));

#define H_N   20
#define NE    100
#define T_OFF 0
#define D_OFF 102400
#define H_OFF 204800

__device__ __forceinline__ int triIdx(int i, int j) {  // i <= j, row-major triu
    return i * H_N - ((i * (i - 1)) >> 1) + (j - i);
}

// ---------------- asm building blocks ----------------
// v[0:15] rotating y-quad window; v[16:17] pivot; v[18:19] p; v20 den;
// v[22:29] t0..t3; v[30:33] temps; v34 scratch. s[90:91] exec save.

// slot write: publish own row k of col 5c+m (addr abm=ab+8m, offset 40c)
#define WSLOT(AK, OFF) "ds_write_b64 %[abm], %[" #AK "] offset:" #OFF "\n\t"
// mixed-slot write, only lanes m > m*
#define WMIX(AK, OFF, MS) \
  "v_cmp_lt_u32 vcc, " #MS ", %[vm]\n\t" \
  "s_and_saveexec_b64 s[90:91], vcc\n\t" \
  "ds_write_b64 %[abm], %[" #AK "] offset:" #OFF "\n\t" \
  "s_mov_b64 exec, s[90:91]\n\t"
// burst (owner lane m == m*) begin/end
#define BSTB(MS) \
  "v_cmp_eq_u32 vcc, " #MS ", %[vm]\n\t" \
  "s_and_saveexec_b64 s[90:91], vcc\n\t"
#define BSTE "s_mov_b64 exec, s[90:91]\n\t"
#define BW(AK, OFF) "ds_write_b64 %[ab], %[" #AK "] offset:" #OFF "\n\t"
// pivot read y[k] (uniform addr -> broadcast)
#define PIV(OFF) "ds_read_b64 v[16:17], %[ab] offset:" #OFF "\n\t"
// extras: per-lane y[j_c] into t_c
#define EXR(T0, T1, OFF) "ds_read_b64 v[" #T0 ":" #T1 "], %[abm] offset:" #OFF "\n\t"
#define EX0 EXR(22,23,0)
#define EX1 EX0 EXR(24,25,40)
#define EX2 EX1 EXR(26,27,80)
#define EX3 EX2 EXR(28,29,120)
#define QISS4 \
  "ds_read_b128 v[0:3], %[ab] offset:0\n\t" \
  "ds_read_b128 v[4:7], %[ab] offset:16\n\t" \
  "ds_read_b128 v[8:11], %[ab] offset:32\n\t" \
  "ds_read_b128 v[12:15], %[ab] offset:48\n\t"
// wait pivot (WP = c*+5 outstanding after it), complex reciprocal p=v[18:19]
#define PCHAIN(WP) \
  "s_waitcnt lgkmcnt(" #WP ")\n\t" \
  "v_mul_f32 v20, v16, v16\n\t" \
  "v_fmac_f32 v20, v17, v17\n\t" \
  "v_rcp_f32 v20, v20\n\t" \
  "s_nop 1\n\t" \
  "v_mul_f32 v18, v16, v20\n\t" \
  "v_mul_f32 v19, -v17, v20\n\t"
// t_c = cmul(A_c[k], p)  (slots c > c*)
#define TP(T0, T1, AK) \
  "v_pk_mul_f32 v[30:31], %[" #AK "], v[18:19] op_sel:[1,1] op_sel_hi:[1,0] neg_lo:[1,0]\n\t" \
  "v_pk_fma_f32 v[" #T0 ":" #T1 "], %[" #AK "], v[18:19], v[30:31] op_sel_hi:[0,1,1]\n\t"
// t_c = cmul(-e, p), e preloaded in t_c  (slots c < c*)
#define TN(T0, T1) \
  "v_pk_mul_f32 v[30:31], v[" #T0 ":" #T1 "], v[18:19] op_sel:[1,1] op_sel_hi:[1,0] neg_hi:[1,0]\n\t" \
  "v_pk_fma_f32 v[" #T0 ":" #T1 "], v[" #T0 ":" #T1 "], v[18:19], v[30:31] op_sel_hi:[0,1,1] neg_lo:[1,0,0] neg_hi:[1,0,0]\n\t"
// mixed slot c*: t = m>m* ? cmul(A[k],p) : cmul(-e,p); owner: [1+px, py]
#define TM(T0, T1, AK, MS) \
  TN(T0, T1) \
  "v_pk_mul_f32 v[30:31], %[" #AK "], v[18:19] op_sel:[1,1] op_sel_hi:[1,0] neg_lo:[1,0]\n\t" \
  "v_pk_fma_f32 v[32:33], %[" #AK "], v[18:19], v[30:31] op_sel_hi:[0,1,1]\n\t" \
  "v_cmp_lt_u32 vcc, " #MS ", %[vm]\n\t" \
  "v_cndmask_b32 v" #T0 ", v" #T0 ", v32, vcc\n\t" \
  "v_cndmask_b32 v" #T1 ", v" #T1 ", v33, vcc\n\t" \
  "v_add_f32 v34, 1.0, v18\n\t" \
  "v_cmp_eq_u32 vcc, " #MS ", %[vm]\n\t" \
  "v_cndmask_b32 v" #T0 ", v" #T0 ", v34, vcc\n\t" \
  "v_cndmask_b32 v" #T1 ", v" #T1 ", v19, vcc\n\t"
#define WAITEX "s_waitcnt lgkmcnt(4)\n\t"
// A_c[k] <- t_c (pair copy via *1.0; op_sel_hi forces const LO in hi half)
#define PSET(AK, T0, T1) \
  "v_pk_mul_f32 %[" #AK "], v[" #T0 ":" #T1 "], 1.0 op_sel_hi:[1,0]\n\t"
// owner: A_c*[k] <- p, others t
#define POWN(AK, T0, T1, MS) \
  "v_cmp_eq_u32 vcc, " #MS ", %[vm]\n\t" \
  "v_cndmask_b32 v" #T0 ", v" #T0 ", v18, vcc\n\t" \
  "v_cndmask_b32 v" #T1 ", v" #T1 ", v19, vcc\n\t" \
  PSET(AK, T0, T1)
// row update: A -= y*t  (sign-free, pivot-column broadcast)
#define U(A, Y0, Y1, T0, T1) \
  "v_pk_fma_f32 %[" #A "], v[" #Y0 ":" #Y1 "], v[" #T0 ":" #T1 "], %[" #A "] op_sel:[1,1,0] op_sel_hi:[1,0,1] neg_hi:[1,0,0]\n\t" \
  "v_pk_fma_f32 %[" #A "], v[" #Y0 ":" #Y1 "], v[" #T0 ":" #T1 "], %[" #A "] op_sel_hi:[0,1,1] neg_lo:[1,0,0] neg_hi:[1,0,0]\n\t"

// burst chains: rows 0..k of the pivot column (owner's slot registers)
#define BUA0 BW(a0_0,0)
#define BUA1 BUA0 BW(a0_1,8)
#define BUA2 BUA1 BW(a0_2,16)
#define BUA3 BUA2 BW(a0_3,24)
#define BUA4 BUA3 BW(a0_4,32)
#define BUB0 BW(a1_0,0)
#define BUB1 BUB0 BW(a1_1,8)
#define BUB2 BUB1 BW(a1_2,16)
#define BUB3 BUB2 BW(a1_3,24)
#define BUB4 BUB3 BW(a1_4,32)
#define BUB5 BUB4 BW(a1_5,40)
#define BUB6 BUB5 BW(a1_6,48)
#define BUB7 BUB6 BW(a1_7,56)
#define BUB8 BUB7 BW(a1_8,64)
#define BUB9 BUB8 BW(a1_9,72)
#define BUC0 BW(a2_0,0)
#define BUC1 BUC0 BW(a2_1,8)
#define BUC2 BUC1 BW(a2_2,16)
#define BUC3 BUC2 BW(a2_3,24)
#define BUC4 BUC3 BW(a2_4,32)
#define BUC5 BUC4 BW(a2_5,40)
#define BUC6 BUC5 BW(a2_6,48)
#define BUC7 BUC6 BW(a2_7,56)
#define BUC8 BUC7 BW(a2_8,64)
#define BUC9 BUC8 BW(a2_9,72)
#define BUC10 BUC9 BW(a2_10,80)
#define BUC11 BUC10 BW(a2_11,88)
#define BUC12 BUC11 BW(a2_12,96)
#define BUC13 BUC12 BW(a2_13,104)
#define BUC14 BUC13 BW(a2_14,112)
#define BUD0 BW(a3_0,0)
#define BUD1 BUD0 BW(a3_1,8)
#define BUD2 BUD1 BW(a3_2,16)
#define BUD3 BUD2 BW(a3_3,24)
#define BUD4 BUD3 BW(a3_4,32)
#define BUD5 BUD4 BW(a3_5,40)
#define BUD6 BUD5 BW(a3_6,48)
#define BUD7 BUD6 BW(a3_7,56)
#define BUD8 BUD7 BW(a3_8,64)
#define BUD9 BUD8 BW(a3_9,72)
#define BUD10 BUD9 BW(a3_10,80)
#define BUD11 BUD10 BW(a3_11,88)
#define BUD12 BUD11 BW(a3_12,96)
#define BUD13 BUD12 BW(a3_13,104)
#define BUD14 BUD13 BW(a3_14,112)
#define BUD15 BUD14 BW(a3_15,120)
#define BUD16 BUD15 BW(a3_16,128)
#define BUD17 BUD16 BW(a3_17,136)
#define BUD18 BUD17 BW(a3_18,144)
#define BUD19 BUD18 BW(a3_19,152)

// k-independent quad stream: 50 row-updates, rotating 4-slot window,
// counted waits, re-issue next quad after consuming a slot.
#define ALLQ \
  "s_waitcnt lgkmcnt(3)\n\t" \
  U(a3_0,0,1,28,29) U(a3_1,2,3,28,29) U(a2_0,0,1,26,27) U(a2_1,2,3,26,27) \
  U(a1_0,0,1,24,25) U(a1_1,2,3,24,25) U(a0_0,0,1,22,23) U(a0_1,2,3,22,23) \
  "ds_read_b128 v[0:3], %[ab] offset:64\n\t" \
  "s_waitcnt lgkmcnt(3)\n\t" \
  U(a3_2,4,5,28,29) U(a3_3,6,7,28,29) U(a2_2,4,5,26,27) U(a2_3,6,7,26,27) \
  U(a1_2,4,5,24,25) U(a1_3,6,7,24,25) U(a0_2,4,5,22,23) U(a0_3,6,7,22,23) \
  "ds_read_b128 v[4:7], %[ab] offset:80\n\t" \
  "s_waitcnt lgkmcnt(3)\n\t" \
  U(a3_4,8,9,28,29) U(a3_5,10,11,28,29) U(a2_4,8,9,26,27) U(a2_5,10,11,26,27) \
  U(a1_4,8,9,24,25) U(a1_5,10,11,24,25) U(a0_4,8,9,22,23) \
  "ds_read_b128 v[8:11], %[ab] offset:96\n\t" \
  "s_waitcnt lgkmcnt(3)\n\t" \
  U(a3_6,12,13,28,29) U(a3_7,14,15,28,29) U(a2_6,12,13,26,27) U(a2_7,14,15,26,27) \
  U(a1_6,12,13,24,25) U(a1_7,14,15,24,25) \
  "ds_read_b128 v[12:15], %[ab] offset:112\n\t" \
  "s_waitcnt lgkmcnt(3)\n\t" \
  U(a3_8,0,1,28,29) U(a3_9,2,3,28,29) U(a2_8,0,1,26,27) U(a2_9,2,3,26,27) \
  U(a1_8,0,1,24,25) U(a1_9,2,3,24,25) \
  "ds_read_b128 v[0:3], %[ab] offset:128\n\t" \
  "s_waitcnt lgkmcnt(3)\n\t" \
  U(a3_10,4,5,28,29) U(a3_11,6,7,28,29) U(a2_10,4,5,26,27) U(a2_11,6,7,26,27) \
  "ds_read_b128 v[4:7], %[ab] offset:144\n\t" \
  "s_waitcnt lgkmcnt(3)\n\t" \
  U(a3_12,8,9,28,29) U(a3_13,10,11,28,29) U(a2_12,8,9,26,27) U(a2_13,10,11,26,27) \
  "s_waitcnt lgkmcnt(2)\n\t" \
  U(a3_14,12,13,28,29) U(a3_15,14,15,28,29) U(a2_14,12,13,26,27) \
  "s_waitcnt lgkmcnt(1)\n\t" \
  U(a3_16,0,1,28,29) U(a3_17,2,3,28,29) \
  "s_waitcnt lgkmcnt(0)\n\t" \
  U(a3_18,4,5,28,29) U(a3_19,6,7,28,29)

// ---- per-step compositions: S(k), c* = k/5, m* = k%5 ----
#define S0  WSLOT(a1_0,40) WSLOT(a2_0,80) WSLOT(a3_0,120) WMIX(a0_0,0,0) BSTB(0) BUA0 BSTE PIV(0)  EX0 QISS4 PCHAIN(5) TP(24,25,a1_0) TP(26,27,a2_0) TP(28,29,a3_0) WAITEX TM(22,23,a0_0,0) ALLQ PSET(a1_0,24,25) PSET(a2_0,26,27) PSET(a3_0,28,29) POWN(a0_0,22,23,0)
#define S1  WSLOT(a1_1,40) WSLOT(a2_1,80) WSLOT(a3_1,120) WMIX(a0_1,0,1) BSTB(1) BUA1 BSTE PIV(8)  EX0 QISS4 PCHAIN(5) TP(24,25,a1_1) TP(26,27,a2_1) TP(28,29,a3_1) WAITEX TM(22,23,a0_1,1) ALLQ PSET(a1_1,24,25) PSET(a2_1,26,27) PSET(a3_1,28,29) POWN(a0_1,22,23,1)
#define S2  WSLOT(a1_2,40) WSLOT(a2_2,80) WSLOT(a3_2,120) WMIX(a0_2,0,2) BSTB(2) BUA2 BSTE PIV(16) EX0 QISS4 PCHAIN(5) TP(24,25,a1_2) TP(26,27,a2_2) TP(28,29,a3_2) WAITEX TM(22,23,a0_2,2) ALLQ PSET(a1_2,24,25) PSET(a2_2,26,27) PSET(a3_2,28,29) POWN(a0_2,22,23,2)
#define S3  WSLOT(a1_3,40) WSLOT(a2_3,80) WSLOT(a3_3,120) WMIX(a0_3,0,3) BSTB(3) BUA3 BSTE PIV(24) EX0 QISS4 PCHAIN(5) TP(24,25,a1_3) TP(26,27,a2_3) TP(28,29,a3_3) WAITEX TM(22,23,a0_3,3) ALLQ PSET(a1_3,24,25) PSET(a2_3,26,27) PSET(a3_3,28,29) POWN(a0_3,22,23,3)
#define S4  WSLOT(a1_4,40) WSLOT(a2_4,80) WSLOT(a3_4,120)                BSTB(4) BUA4 BSTE PIV(32) EX0 QISS4 PCHAIN(5) TP(24,25,a1_4) TP(26,27,a2_4) TP(28,29,a3_4) WAITEX TM(22,23,a0_4,4) ALLQ PSET(a1_4,24,25) PSET(a2_4,26,27) PSET(a3_4,28,29) POWN(a0_4,22,23,4)
#define S5  WSLOT(a2_5,80) WSLOT(a3_5,120) WMIX(a1_5,40,0) BSTB(0) BUB5 BSTE PIV(40) EX1 QISS4 PCHAIN(6) TP(26,27,a2_5) TP(28,29,a3_5) WAITEX TN(22,23) TM(24,25,a1_5,0) ALLQ PSET(a2_5,26,27) PSET(a3_5,28,29) POWN(a1_5,24,25,0)
#define S6  WSLOT(a2_6,80) WSLOT(a3_6,120) WMIX(a1_6,40,1) BSTB(1) BUB6 BSTE PIV(48) EX1 QISS4 PCHAIN(6) TP(26,27,a2_6) TP(28,29,a3_6) WAITEX TN(22,23) TM(24,25,a1_6,1) ALLQ PSET(a2_6,26,27) PSET(a3_6,28,29) POWN(a1_6,24,25,1)
#define S7  WSLOT(a2_7,80) WSLOT(a3_7,120) WMIX(a1_7,40,2) BSTB(2) BUB7 BSTE PIV(56) EX1 QISS4 PCHAIN(6) TP(26,27,a2_7) TP(28,29,a3_7) WAITEX TN(22,23) TM(24,25,a1_7,2) ALLQ PSET(a2_7,26,27) PSET(a3_7,28,29) POWN(a1_7,24,25,2)
#define S8  WSLOT(a2_8,80) WSLOT(a3_8,120) WMIX(a1_8,40,3) BSTB(3) BUB8 BSTE PIV(64) EX1 QISS4 PCHAIN(6) TP(26,27,a2_8) TP(28,29,a3_8) WAITEX TN(22,23) TM(24,25,a1_8,3) ALLQ PSET(a2_8,26,27) PSET(a3_8,28,29) POWN(a1_8,24,25,3)
#define S9  WSLOT(a2_9,80) WSLOT(a3_9,120)                 BSTB(4) BUB9 BSTE PIV(72) EX1 QISS4 PCHAIN(6) TP(26,27,a2_9) TP(28,29,a3_9) WAITEX TN(22,23) TM(24,25,a1_9,4) ALLQ PSET(a2_9,26,27) PSET(a3_9,28,29) POWN(a1_9,24,25,4)
#define S10 WSLOT(a3_10,120) WMIX(a2_10,80,0) BSTB(0) BUC10 BSTE PIV(80)  EX2 QISS4 PCHAIN(7) TP(28,29,a3_10) WAITEX TN(22,23) TN(24,25) TM(26,27,a2_10,0) ALLQ PSET(a3_10,28,29) POWN(a2_10,26,27,0)
#define S11 WSLOT(a3_11,120) WMIX(a2_11,80,1) BSTB(1) BUC11 BSTE PIV(88)  EX2 QISS4 PCHAIN(7) TP(28,29,a3_11) WAITEX TN(22,23) TN(24,25) TM(26,27,a2_11,1) ALLQ PSET(a3_11,28,29) POWN(a2_11,26,27,1)
#define S12 WSLOT(a3_12,120) WMIX(a2_12,80,2) BSTB(2) BUC12 BSTE PIV(96)  EX2 QISS4 PCHAIN(7) TP(28,29,a3_12) WAITEX TN(22,23) TN(24,25) TM(26,27,a2_12,2) ALLQ PSET(a3_12,28,29) POWN(a2_12,26,27,2)
#define S13 WSLOT(a3_13,120) WMIX(a2_13,80,3) BSTB(3) BUC13 BSTE PIV(104) EX2 QISS4 PCHAIN(7) TP(28,29,a3_13) WAITEX TN(22,23) TN(24,25) TM(26,27,a2_13,3) ALLQ PSET(a3_13,28,29) POWN(a2_13,26,27,3)
#define S14 WSLOT(a3_14,120)                  BSTB(4) BUC14 BSTE PIV(112) EX2 QISS4 PCHAIN(7) TP(28,29,a3_14) WAITEX TN(22,23) TN(24,25) TM(26,27,a2_14,4) ALLQ PSET(a3_14,28,29) POWN(a2_14,26,27,4)
#define S15 WMIX(a3_15,120,0) BSTB(0) BUD15 BSTE PIV(120) EX3 QISS4 PCHAIN(8) WAITEX TN(22,23) TN(24,25) TN(26,27) TM(28,29,a3_15,0) ALLQ POWN(a3_15,28,29,0)
#define S16 WMIX(a3_16,120,1) BSTB(1) BUD16 BSTE PIV(128) EX3 QISS4 PCHAIN(8) WAITEX TN(22,23) TN(24,25) TN(26,27) TM(28,29,a3_16,1) ALLQ POWN(a3_16,28,29,1)
#define S17 WMIX(a3_17,120,2) BSTB(2) BUD17 BSTE PIV(136) EX3 QISS4 PCHAIN(8) WAITEX TN(22,23) TN(24,25) TN(26,27) TM(28,29,a3_17,2) ALLQ POWN(a3_17,28,29,2)
#define S18 WMIX(a3_18,120,3) BSTB(3) BUD18 BSTE PIV(144) EX3 QISS4 PCHAIN(8) WAITEX TN(22,23) TN(24,25) TN(26,27) TM(28,29,a3_18,3) ALLQ POWN(a3_18,28,29,3)
#define S19                   BSTB(4) BUD19 BSTE PIV(152) EX3 QISS4 PCHAIN(8) WAITEX TN(22,23) TN(24,25) TN(26,27) TM(28,29,a3_19,4) ALLQ POWN(a3_19,28,29,4)

__global__ __launch_bounds__(64)
void negf_all(const float* __restrict__ tri,
              const float* __restrict__ GL,
              const float* __restrict__ GR,
              float* __restrict__ out)
{
    __shared__ float Hcm[400];                 // col-major: Hcm[c*20+r]
    __shared__ float sgL[H_N], sgR[H_N];
    __shared__ __align__(16) float stage[12 * 44];  // 176B-strided regions

    const int blk   = blockIdx.x;
    const int b     = blk / 9;
    const int chunk = blk - b * 9;
    const int tid   = threadIdx.x;             // == lane (1-wave block)

    // ---- per-wave staging of H (col-major) + gammas ----
    const float* triB = tri + b * 210;
    for (int u = tid; u < 400; u += 64) {
        int c = u / 20, r = u - c * 20;
        int lo = r < c ? r : c;
        int hi = r < c ? c : r;
        Hcm[u] = triB[triIdx(lo, hi)];
    }
    if (tid < H_N) { sgL[tid] = GL[b * H_N + tid]; sgR[tid] = GR[b * H_N + tid]; }
    asm volatile("s_waitcnt lgkmcnt(0)" ::: "memory");   // wave-coherent LDS

    // ---- H output (row-major, exact copy); one block per b ----
    if (chunk == 0) {
        for (int u = tid; u < 400; u += 64) {
            int r = u / 20, c = u - r * 20;
            out[H_OFF + b * 400 + u] = Hcm[c * 20 + r];
        }
    }

    const int sgw = tid / 5;                   // 0..11 active, 12 idle (60-63)
    const int m   = tid - sgw * 5;             // 0..4
    const int e   = chunk * 12 + sgw;
    if (sgw >= 12 || e >= NE) return;

    const int j0 = m, j1 = 5 + m, j2 = 10 + m, j3 = 15 + m;
    const float gam0 = 0.5f * (sgL[j0] + sgR[j0]);
    const float gam1 = 0.5f * (sgL[j1] + sgR[j1]);
    const float gam2 = 0.5f * (sgL[j2] + sgR[j2]);
    const float gam3 = 0.5f * (sgL[j3] + sgR[j3]);
    const float E = fmaf((float)e, 6.0f / 99.0f, -3.0f);

    // ---- init triangle columns (invalid rows -> 0, kept finite) ----
    f32x2 A0[5], A1[10], A2[15], A3[20];
#define MK(DST, I, J, G) { \
        float h = Hcm[(J) * 20 + (I)]; \
        bool vl = (I) <= (J); bool dg = (I) == (J); \
        DST.x = vl ? (dg ? (E - h) : -h) : 0.0f; \
        DST.y = vl ? (dg ? (G) : 0.0f) : 0.0f; }
    #pragma unroll
    for (int i = 0; i < 5;  ++i) MK(A0[i], i, j0, gam0)
    #pragma unroll
    for (int i = 0; i < 10; ++i) MK(A1[i], i, j1, gam1)
    #pragma unroll
    for (int i = 0; i < 15; ++i) MK(A2[i], i, j2, gam2)
    #pragma unroll
    for (int i = 0; i < 20; ++i) MK(A3[i], i, j3, gam3)
#undef MK

    const unsigned ab  = (unsigned)(size_t)&stage[sgw * 44];
    const unsigned abm = ab + 8u * (unsigned)m;
    const unsigned vmu = (unsigned)m;

    asm volatile(
        "s_waitcnt lgkmcnt(0)\n\t"
        S0 S1 S2 S3 S4 S5 S6 S7 S8 S9
        S10 S11 S12 S13 S14 S15 S16 S17 S18 S19
        : [a0_0]"+v"(A0[0]), [a0_1]"+v"(A0[1]), [a0_2]"+v"(A0[2]), [a0_3]"+v"(A0[3]), [a0_4]"+v"(A0[4]),
          [a1_0]"+v"(A1[0]), [a1_1]"+v"(A1[1]), [a1_2]"+v"(A1[2]), [a1_3]"+v"(A1[3]), [a1_4]"+v"(A1[4]),
          [a1_5]"+v"(A1[5]), [a1_6]"+v"(A1[6]), [a1_7]"+v"(A1[7]), [a1_8]"+v"(A1[8]), [a1_9]"+v"(A1[9]),
          [a2_0]"+v"(A2[0]), [a2_1]"+v"(A2[1]), [a2_2]"+v"(A2[2]), [a2_3]"+v"(A2[3]), [a2_4]"+v"(A2[4]),
          [a2_5]"+v"(A2[5]), [a2_6]"+v"(A2[6]), [a2_7]"+v"(A2[7]), [a2_8]"+v"(A2[8]), [a2_9]"+v"(A2[9]),
          [a2_10]"+v"(A2[10]), [a2_11]"+v"(A2[11]), [a2_12]"+v"(A2[12]), [a2_13]"+v"(A2[13]), [a2_14]"+v"(A2[14]),
          [a3_0]"+v"(A3[0]), [a3_1]"+v"(A3[1]), [a3_2]"+v"(A3[2]), [a3_3]"+v"(A3[3]), [a3_4]"+v"(A3[4]),
          [a3_5]"+v"(A3[5]), [a3_6]"+v"(A3[6]), [a3_7]"+v"(A3[7]), [a3_8]"+v"(A3[8]), [a3_9]"+v"(A3[9]),
          [a3_10]"+v"(A3[10]), [a3_11]"+v"(A3[11]), [a3_12]"+v"(A3[12]), [a3_13]"+v"(A3[13]), [a3_14]"+v"(A3[14]),
          [a3_15]"+v"(A3[15]), [a3_16]"+v"(A3[16]), [a3_17]"+v"(A3[17]), [a3_18]"+v"(A3[18]), [a3_19]"+v"(A3[19])
        : [ab]"v"(ab), [abm]"v"(abm), [vm]"v"(vmu)
        : "vcc", "s90", "s91", "memory",
          "v0","v1","v2","v3","v4","v5","v6","v7","v8","v9",
          "v10","v11","v12","v13","v14","v15","v16","v17","v18","v19",
          "v20","v21","v22","v23","v24","v25","v26","v27","v28","v29",
          "v30","v31","v32","v33","v34","v35");

    // ---- epilogue: triangle-weighted T + diag Im, 5-lane reduce ----
    // G symmetric at end: T = sum_{i<=j} |G_ij|^2 (gL_i gR_j + [i<j] gL_j gR_i)
    float tv = 0.0f, dv = 0.0f;
    const float gRj0 = sgR[j0], gRj1 = sgR[j1], gRj2 = sgR[j2], gRj3 = sgR[j3];
    const float gLj0 = sgL[j0], gLj1 = sgL[j1], gLj2 = sgL[j2], gLj3 = sgL[j3];
#define ACC(A, I, J, GRJ, GLJ) { \
        float mag = fmaf(A.x, A.x, A.y * A.y); \
        float w = ((I) <= (J)) ? fmaf(sgL[I], GRJ, ((I) < (J)) ? GLJ * sgR[I] : 0.0f) : 0.0f; \
        tv = fmaf(mag, w, tv); \
        dv += ((I) == (J)) ? A.y : 0.0f; }
    #pragma unroll
    for (int i = 0; i < 5;  ++i) ACC(A0[i], i, j0, gRj0, gLj0)
    #pragma unroll
    for (int i = 0; i < 10; ++i) ACC(A1[i], i, j1, gRj1, gLj1)
    #pragma unroll
    for (int i = 0; i < 15; ++i) ACC(A2[i], i, j2, gRj2, gLj2)
    #pragma unroll
    for (int i = 0; i < 20; ++i) ACC(A3[i], i, j3, gRj3, gLj3)
#undef ACC

    #pragma unroll
    for (int d = 4; d >= 1; d >>= 1) {
        float t2 = __shfl(tv, tid + d, 64);
        float d2 = __shfl(dv, tid + d, 64);
        if (m + d < 5) { tv += t2; dv += d2; }
    }
    if (m == 0) {
        out[T_OFF + b * NE + e] = __log10f(fmaxf(tv, 1e-16f));
        out[D_OFF + b * NE + e] = __log10f(fmaxf(-dv, 1e-16f));
    }
}

extern "C" void kernel_launch(void* const* d_in, const int* in_sizes, int n_in,
                              void* d_out, int out_size, void* d_ws, size_t ws_size,
                              hipStream_t stream) {
    const float* tri = (const float*)d_in[0];
    const float* gL  = (const float*)d_in[1];
    const float* gR  = (const float*)d_in[2];
    float* out = (float*)d_out;
    negf_all<<<1024 * 9, 64, 0, stream>>>(tri, gL, gR, out);
}